// Round 5
// baseline (611.202 us; speedup 1.0000x reference)
//
#include <hip/hip_runtime.h>
#include <cstdint>

#define S_LEN 2048
#define D_DIM 4096
#define NHEAD 32
#define NKVH  8
#define HDIM  128
#define NQKV  6144

typedef __bf16 bf16x8 __attribute__((ext_vector_type(8)));
typedef float floatx4 __attribute__((ext_vector_type(4)));
typedef unsigned short u16;
typedef unsigned int u32;

__device__ __forceinline__ u16 f2bf(float f) {
  u32 u = __builtin_bit_cast(u32, f);
  u += 0x7fffu + ((u >> 16) & 1u);
  return (u16)(u >> 16);
}
__device__ __forceinline__ float bf2f(u16 h) {
  u32 u = ((u32)h) << 16;
  return __builtin_bit_cast(float, u);
}

// async global->LDS, 16B per lane; LDS dest = wave-uniform base + lane*16
__device__ __forceinline__ void gll16(const void* g, const void* l) {
  __builtin_amdgcn_global_load_lds(
      (const __attribute__((address_space(1))) u32*)(unsigned long long)(uintptr_t)g,
      (__attribute__((address_space(3))) u32*)(u32)(uintptr_t)l, 16, 0, 0);
}

// ---------------- prep: x cast + all 4 weight transposes, one launch ----------------

__global__ __launch_bounds__(256) void prep_kernel(const float* __restrict__ x,
                                                   const float* __restrict__ Wq,
                                                   const float* __restrict__ Wk,
                                                   const float* __restrict__ Wv,
                                                   const float* __restrict__ Wo,
                                                   u16* __restrict__ x_bf,
                                                   u16* __restrict__ wqkvT,
                                                   u16* __restrict__ woT) {
  int id = blockIdx.x;
  if (id < 8192) {
    // cast x [2048*4096] f32 -> bf16
    int i = (id * 256 + (int)threadIdx.x) * 4;
    float4 v = *(const float4*)(x + i);
    u32 lo = (u32)f2bf(v.x) | ((u32)f2bf(v.y) << 16);
    u32 hi = (u32)f2bf(v.z) | ((u32)f2bf(v.w) << 16);
    *(uint2*)(x_bf + i) = make_uint2(lo, hi);
    return;
  }
  id -= 8192;
  __shared__ float tile[64][65];
  const float* src;
  u16* dst;
  int N;
  if (id < 4096) {
    src = Wq; dst = wqkvT; N = 4096;
  } else if (id < 5120) {
    src = Wk; dst = wqkvT + (size_t)4096 * 4096; N = 1024; id -= 4096;
  } else if (id < 6144) {
    src = Wv; dst = wqkvT + (size_t)5120 * 4096; N = 1024; id -= 5120;
  } else {
    src = Wo; dst = woT; N = 4096; id -= 6144;
  }
  const int nb = id / 64, kb = id % 64;
  const int k0 = kb * 64, n0 = nb * 64;
  const int t = threadIdx.x;
  const int c4 = (t & 15) * 4, r0 = t >> 4;
#pragma unroll
  for (int p = 0; p < 4; ++p) {
    int r = r0 + p * 16;
    float4 v = *(const float4*)(src + (size_t)(k0 + r) * N + n0 + c4);
    tile[r][c4 + 0] = v.x;
    tile[r][c4 + 1] = v.y;
    tile[r][c4 + 2] = v.z;
    tile[r][c4 + 3] = v.w;
  }
  __syncthreads();
#pragma unroll
  for (int p = 0; p < 4; ++p) {
    int rr = r0 + p * 16;
    u32 a = (u32)f2bf(tile[c4 + 0][rr]) | ((u32)f2bf(tile[c4 + 1][rr]) << 16);
    u32 b = (u32)f2bf(tile[c4 + 2][rr]) | ((u32)f2bf(tile[c4 + 3][rr]) << 16);
    *(uint2*)(dst + (size_t)(n0 + rr) * 4096 + k0 + c4) = make_uint2(a, b);
  }
}

// ---------------- fallback prep kernels (non-split GEMM1 path) ----------------

__global__ __launch_bounds__(256) void vt_kernel(const u16* __restrict__ qkv,
                                                 u16* __restrict__ vt) {
  __shared__ u16 tile[64][65];
  int s0 = blockIdx.x * 64, d0 = blockIdx.y * 64, hk = blockIdx.z;
  int t = threadIdx.x, c = t & 63, r0 = t >> 6;
#pragma unroll
  for (int p = 0; p < 16; ++p) {
    int r = r0 + p * 4;
    tile[r][c] = qkv[(size_t)(s0 + r) * NQKV + 5120 + hk * HDIM + d0 + c];
  }
  __syncthreads();
#pragma unroll
  for (int p = 0; p < 16; ++p) {
    int rr = r0 + p * 4;
    vt[((size_t)hk * HDIM + d0 + rr) * S_LEN + s0 + c] = tile[c][rr];
  }
}

__global__ __launch_bounds__(256) void rope_kernel(u16* __restrict__ qkv) {
  int s = blockIdx.x;
  int sub = threadIdx.x >> 6;
  int i = threadIdx.x & 63;
  int hh = blockIdx.y * 4 + sub;
  int colbase = (hh < NHEAD) ? hh * HDIM : D_DIM + (hh - NHEAD) * HDIM;
  u32* p = (u32*)(qkv + (size_t)s * NQKV + colbase) + i;
  u32 pr = *p;
  float x0 = bf2f((u16)(pr & 0xffffu));
  float x1 = bf2f((u16)(pr >> 16));
  float invf = expf(-(float)(2 * i) * (13.122363377404328f / 128.0f));
  float ang = (float)s * invf;
  float cs = cosf(ang), sn = sinf(ang);
  float o0 = x0 * cs - x1 * sn;
  float o1 = x0 * sn + x1 * cs;
  *p = (u32)f2bf(o0) | ((u32)f2bf(o1) << 16);
}

// ---------------- GEMM: C[M,N] (bf16) = A[M,K(lda)] * Bt[N,K(ldb)]^T ----------------
// gridDim.z = split-K count; blockIdx.z selects k-slice of length kk and
// writes partial z into Cout + z*M*N.

__global__ __launch_bounds__(256) void gemm_bt(const u16* __restrict__ A,
                                               const u16* __restrict__ Bt,
                                               u16* __restrict__ Cout,
                                               int M, int N, int kk, int lda, int ldb) {
  __shared__ u16 As[128 * 32];
  __shared__ u16 Bs[128 * 32];
  const int tid = threadIdx.x;
  const int w = tid >> 6, lane = tid & 63;
  const int quad = lane >> 4, l15 = lane & 15;
  const int m0 = blockIdx.y * 128, n0 = blockIdx.x * 128;
  const int wm = (w & 1) * 64, wn = (w >> 1) * 64;
  const int kz = blockIdx.z * kk;
  Cout += (size_t)blockIdx.z * M * N;
  floatx4 acc[4][4];
#pragma unroll
  for (int mi = 0; mi < 4; ++mi)
#pragma unroll
    for (int ni = 0; ni < 4; ++ni)
#pragma unroll
      for (int j = 0; j < 4; ++j) acc[mi][ni][j] = 0.0f;

  const int srow = w * 32 + (lane >> 2);
  const int kcol = (lane & 3) * 8;
  const u16* pA0 = A + (size_t)(m0 + srow) * lda + kz + kcol;
  const u16* pA1 = pA0 + (size_t)16 * lda;
  const u16* pB0 = Bt + (size_t)(n0 + srow) * ldb + kz + kcol;
  const u16* pB1 = pB0 + (size_t)16 * ldb;

  for (int k0 = 0; k0 < kk; k0 += 32) {
    gll16(pA0 + k0, As + (w * 32) * 32);
    gll16(pA1 + k0, As + (w * 32 + 16) * 32);
    gll16(pB0 + k0, Bs + (w * 32) * 32);
    gll16(pB1 + k0, Bs + (w * 32 + 16) * 32);
    __syncthreads();
    bf16x8 a[4], b[4];
#pragma unroll
    for (int mi = 0; mi < 4; ++mi)
      a[mi] = *(const bf16x8*)(As + (wm + mi * 16 + l15) * 32 + quad * 8);
#pragma unroll
    for (int ni = 0; ni < 4; ++ni)
      b[ni] = *(const bf16x8*)(Bs + (wn + ni * 16 + l15) * 32 + quad * 8);
#pragma unroll
    for (int mi = 0; mi < 4; ++mi)
#pragma unroll
      for (int ni = 0; ni < 4; ++ni)
        acc[mi][ni] = __builtin_amdgcn_mfma_f32_16x16x32_bf16(a[mi], b[ni], acc[mi][ni], 0, 0, 0);
    __syncthreads();
  }
#pragma unroll
  for (int mi = 0; mi < 4; ++mi)
#pragma unroll
    for (int ni = 0; ni < 4; ++ni) {
      int row = m0 + wm + mi * 16 + quad * 4;
      int col = n0 + wn + ni * 16 + l15;
#pragma unroll
      for (int j = 0; j < 4; ++j)
        Cout[(size_t)(row + j) * N + col] = f2bf(acc[mi][ni][j]);
    }
}

// ---------------- epilogue1: split-K reduce + RoPE + V-transpose, fused ----------------
// part = [2][2048][6144] bf16 partials. q/k cols: sum + rope -> qkv.
// v cols: sum -> vt transposed. (qkv v-range left unwritten; nothing reads it.)
__global__ __launch_bounds__(256) void epilogue1(const u16* __restrict__ part,
                                                 u16* __restrict__ qkv,
                                                 u16* __restrict__ vt) {
  const int s0 = blockIdx.x * 64;
  const int cb = blockIdx.y;
  const int t = threadIdx.x;
  const size_t PSZ = (size_t)S_LEN * NQKV;
  if (cb < 80) {
    // rope on 64x64 tile of q/k
    const int c0 = cb * 64;
    const int r = t >> 2, pg = t & 3;
    const int s = s0 + r;
    const size_t base = (size_t)s * NQKV + c0 + pg * 16;
    u16 ua[16], ub[16], ov[16];
    *(uint4*)(ua) = *(const uint4*)(part + base);
    *(uint4*)(ua + 8) = *(const uint4*)(part + base + 8);
    *(uint4*)(ub) = *(const uint4*)(part + PSZ + base);
    *(uint4*)(ub + 8) = *(const uint4*)(part + PSZ + base + 8);
    const int i0 = (cb & 1) * 32 + pg * 8;  // pair index within head
#pragma unroll
    for (int j = 0; j < 8; ++j) {
      float x0 = bf2f(ua[2 * j]) + bf2f(ub[2 * j]);
      float x1 = bf2f(ua[2 * j + 1]) + bf2f(ub[2 * j + 1]);
      float invf = expf(-(float)(2 * (i0 + j)) * (13.122363377404328f / 128.0f));
      float ang = (float)s * invf;
      float cs = cosf(ang), sn = sinf(ang);
      ov[2 * j] = f2bf(x0 * cs - x1 * sn);
      ov[2 * j + 1] = f2bf(x0 * sn + x1 * cs);
    }
    *(uint4*)(qkv + base) = *(uint4*)(ov);
    *(uint4*)(qkv + base + 8) = *(uint4*)(ov + 8);
  } else {
    // v: sum + transpose into vt[hk][d][s]
    __shared__ u16 tile[64][65];
    const int vb = cb - 80;
    const int hk = vb >> 1, d0 = (vb & 1) * 64;
    const int c = t & 63, r0 = t >> 6;
    const size_t cbase = (size_t)5120 + hk * HDIM + d0;
#pragma unroll
    for (int p = 0; p < 16; ++p) {
      int r = r0 + p * 4;
      size_t idx = (size_t)(s0 + r) * NQKV + cbase + c;
      tile[r][c] = f2bf(bf2f(part[idx]) + bf2f(part[PSZ + idx]));
    }
    __syncthreads();
#pragma unroll
    for (int p = 0; p < 16; ++p) {
      int rr = r0 + p * 4;
      vt[((size_t)hk * HDIM + d0 + rr) * S_LEN + s0 + c] = tile[c][rr];
    }
  }
}

// ---------------- reduce2: sum two bf16 partials -> fp32 out ----------------

__global__ __launch_bounds__(256) void reduce_out(const u16* __restrict__ part,
                                                  float* __restrict__ out) {
  const size_t PSZ = (size_t)S_LEN * D_DIM;
  size_t i = ((size_t)blockIdx.x * 256 + threadIdx.x) * 8;
  u16 a[8], b[8];
  *(uint4*)a = *(const uint4*)(part + i);
  *(uint4*)b = *(const uint4*)(part + PSZ + i);
  float4 o0, o1;
  o0.x = bf2f(a[0]) + bf2f(b[0]);
  o0.y = bf2f(a[1]) + bf2f(b[1]);
  o0.z = bf2f(a[2]) + bf2f(b[2]);
  o0.w = bf2f(a[3]) + bf2f(b[3]);
  o1.x = bf2f(a[4]) + bf2f(b[4]);
  o1.y = bf2f(a[5]) + bf2f(b[5]);
  o1.z = bf2f(a[6]) + bf2f(b[6]);
  o1.w = bf2f(a[7]) + bf2f(b[7]);
  *(float4*)(out + i) = o0;
  *(float4*)(out + i + 4) = o1;
}

// ---------------- flash attention (unchanged from R4) ----------------

__global__ __launch_bounds__(256) void attn_kernel(const u16* __restrict__ qkv,
                                                   const u16* __restrict__ vt,
                                                   u16* __restrict__ attn_o) {
  __shared__ u16 Ks[4][64 * 32];
  __shared__ u16 Vs[2][128 * 32];
  __shared__ u16 Ps[4][16 * 64];
  const int tid = threadIdx.x, w = tid >> 6, lane = tid & 63;
  const int quad = lane >> 4, l15 = lane & 15;
  const int h = blockIdx.y, hk = h >> 2;
  const int bx = (h & 16) ? blockIdx.x : (gridDim.x - 1 - blockIdx.x);
  const int qb = bx * 128;
  const int mq0 = qb + w * 32;
  const float scale2 = 0.12751744591813488f;  // log2(e)/sqrt(128)
  const int sw = (l15 & 7) * 8;

  bf16x8 qfrag[2][4];
#pragma unroll
  for (int g = 0; g < 2; ++g) {
    const u16* qp = qkv + (size_t)(mq0 + g * 16 + l15) * NQKV + h * HDIM + quad * 8;
#pragma unroll
    for (int c = 0; c < 4; ++c) qfrag[g][c] = *(const bf16x8*)(qp + c * 32);
  }

  floatx4 o[2][8];
#pragma unroll
  for (int g = 0; g < 2; ++g)
#pragma unroll
    for (int nf = 0; nf < 8; ++nf)
#pragma unroll
      for (int j = 0; j < 4; ++j) o[g][nf][j] = 0.0f;
  float m_[2] = {-1e30f, -1e30f}, l_[2] = {0.0f, 0.0f};

  const int nkt = 2 * bx + 2;
  const int srow = lane >> 2;
  const int scol = (lane & 3) * 8;
  const u16* kst = qkv + (size_t)(w * 16 + srow) * NQKV + (D_DIM + hk * HDIM) + scol;
  const u16* vst0 = vt + ((size_t)hk * HDIM + w * 32 + srow) * S_LEN + scol;
  const u16* vst1 = vst0 + (size_t)16 * S_LEN;

  for (int kt = 0; kt < nkt; ++kt) {
    const int kb = kt * 64;
#pragma unroll
    for (int c = 0; c < 4; ++c)
      gll16(kst + (size_t)kb * NQKV + c * 32, &Ks[c][(w * 16) * 32]);
#pragma unroll
    for (int c = 0; c < 2; ++c) {
      gll16(vst0 + kb + c * 32, &Vs[c][(w * 32) * 32]);
      gll16(vst1 + kb + c * 32, &Vs[c][(w * 32 + 16) * 32]);
    }
    __syncthreads();

    if (kb <= mq0) {
      floatx4 sn[2][4];
#pragma unroll
      for (int g = 0; g < 2; ++g)
#pragma unroll
        for (int ki = 0; ki < 4; ++ki)
#pragma unroll
          for (int j = 0; j < 4; ++j) sn[g][ki][j] = 0.0f;
#pragma unroll
      for (int ki = 0; ki < 4; ++ki) {
        if (kb + ki * 16 <= mq0 + 31) {
          const bool g0on = (kb + ki * 16 <= mq0 + 15);
#pragma unroll
          for (int c = 0; c < 4; ++c) {
            bf16x8 kf = *(const bf16x8*)(&Ks[c][(ki * 16 + l15) * 32 + quad * 8]);
            sn[1][ki] = __builtin_amdgcn_mfma_f32_16x16x32_bf16(kf, qfrag[1][c], sn[1][ki], 0, 0, 0);
            if (g0on)
              sn[0][ki] = __builtin_amdgcn_mfma_f32_16x16x32_bf16(kf, qfrag[0][c], sn[0][ki], 0, 0, 0);
          }
        }
      }
      float alw[2];
      bf16x8 pa[2][2];
#pragma unroll
      for (int g = 0; g < 2; ++g) {
        const int qrow = mq0 + g * 16 + l15;
        const int qmax = mq0 + g * 16 + 15;
        float v[16];
        float mv = -1e30f;
#pragma unroll
        for (int ki = 0; ki < 4; ++ki) {
          if (kb + ki * 16 <= qmax) {
#pragma unroll
            for (int dj = 0; dj < 4; ++dj) {
              int key = kb + ki * 16 + quad * 4 + dj;
              float s = sn[g][ki][dj] * scale2;
              float vv = (key > qrow) ? -1e30f : s;
              v[ki * 4 + dj] = vv;
              mv = fmaxf(mv, vv);
            }
          } else {
#pragma unroll
            for (int dj = 0; dj < 4; ++dj) v[ki * 4 + dj] = -1e30f;
          }
        }
        mv = fmaxf(mv, __shfl_xor(mv, 16, 64));
        mv = fmaxf(mv, __shfl_xor(mv, 32, 64));
        float mn = fmaxf(m_[g], mv);
        float a_ = exp2f(m_[g] - mn);
        m_[g] = mn;
        float ps = 0.0f;
#pragma unroll
        for (int ki = 0; ki < 4; ++ki) {
          const int cs = (ki * 16 + quad * 4) ^ sw;
          if (kb + ki * 16 <= qmax) {
            float p0 = exp2f(v[ki * 4 + 0] - mn);
            float p1 = exp2f(v[ki * 4 + 1] - mn);
            float p2 = exp2f(v[ki * 4 + 2] - mn);
            float p3 = exp2f(v[ki * 4 + 3] - mn);
            ps += (p0 + p1) + (p2 + p3);
            u32 pk0 = (u32)f2bf(p0) | ((u32)f2bf(p1) << 16);
            u32 pk1 = (u32)f2bf(p2) | ((u32)f2bf(p3) << 16);
            *(uint2*)(&Ps[w][l15 * 64 + cs]) = make_uint2(pk0, pk1);
          } else {
            *(uint2*)(&Ps[w][l15 * 64 + cs]) = make_uint2(0u, 0u);
          }
        }
        ps += __shfl_xor(ps, 16, 64);
        ps += __shfl_xor(ps, 32, 64);
        l_[g] = l_[g] * a_ + ps;
        alw[g] = a_;
#pragma unroll
        for (int c2 = 0; c2 < 2; ++c2) {
          const int cs = (c2 * 32 + quad * 8) ^ sw;
          pa[g][c2] = *(const bf16x8*)(&Ps[w][l15 * 64 + cs]);
        }
      }
#pragma unroll
      for (int g = 0; g < 2; ++g) {
        float al[4];
#pragma unroll
        for (int dj = 0; dj < 4; ++dj) al[dj] = __shfl(alw[g], quad * 4 + dj, 16);
#pragma unroll
        for (int nf = 0; nf < 8; ++nf)
#pragma unroll
          for (int dj = 0; dj < 4; ++dj) o[g][nf][dj] *= al[dj];
      }
#pragma unroll
      for (int nf = 0; nf < 8; ++nf) {
        bf16x8 vb0 = *(const bf16x8*)(&Vs[0][(nf * 16 + l15) * 32 + quad * 8]);
        bf16x8 vb1 = *(const bf16x8*)(&Vs[1][(nf * 16 + l15) * 32 + quad * 8]);
#pragma unroll
        for (int g = 0; g < 2; ++g) {
          o[g][nf] = __builtin_amdgcn_mfma_f32_16x16x32_bf16(pa[g][0], vb0, o[g][nf], 0, 0, 0);
          o[g][nf] = __builtin_amdgcn_mfma_f32_16x16x32_bf16(pa[g][1], vb1, o[g][nf], 0, 0, 0);
        }
      }
    }
    __syncthreads();
  }

#pragma unroll
  for (int g = 0; g < 2; ++g) {
    float linv = 1.0f / l_[g];
    float rl[4];
#pragma unroll
    for (int dj = 0; dj < 4; ++dj) rl[dj] = __shfl(linv, quad * 4 + dj, 16);
#pragma unroll
    for (int nf = 0; nf < 8; ++nf)
#pragma unroll
      for (int dj = 0; dj < 4; ++dj) {
        int row = mq0 + g * 16 + quad * 4 + dj;
        int col = h * HDIM + nf * 16 + l15;
        attn_o[(size_t)row * D_DIM + col] = f2bf(o[g][nf][dj] * rl[dj]);
      }
  }
}

// ---------------- launcher ----------------

extern "C" void kernel_launch(void* const* d_in, const int* in_sizes, int n_in,
                              void* d_out, int out_size, void* d_ws, size_t ws_size,
                              hipStream_t stream) {
  const float* x  = (const float*)d_in[0];
  const float* Wq = (const float*)d_in[1];
  const float* Wk = (const float*)d_in[2];
  const float* Wv = (const float*)d_in[3];
  const float* Wo = (const float*)d_in[4];
  float* out = (float*)d_out;
  char* ws = (char*)d_ws;
  const size_t MB = 1024 * 1024;
  u16* x_bf   = (u16*)(ws);              // 16 MB   [2048][4096]
  u16* wqkvT  = (u16*)(ws + 16 * MB);    // 48 MB   [6144][4096]
  u16* woT    = (u16*)(ws + 64 * MB);    // 32 MB   [4096][4096]
  u16* qkv    = (u16*)(ws + 96 * MB);    // 24 MB   [2048][6144]
  u16* vt     = (u16*)(ws + 120 * MB);   //  4 MB   [8][128][2048]
  u16* attn_o = (u16*)(ws + 124 * MB);   // 16 MB   [2048][4096]
  u16* part1  = (u16*)(ws + 140 * MB);   // 50.4 MB [2][2048][6144] (only if ws >= 192 MB)
  u16* part2  = (u16*)(ws);              // 33.6 MB [2][2048][4096] aliases dead x_bf/wqkvT

  const bool split1 = ws_size >= 192 * MB;  // runtime-constant: same work every call

  prep_kernel<<<8192 + 10240, 256, 0, stream>>>(x, Wq, Wk, Wv, Wo, x_bf, wqkvT, woT);

  if (split1) {
    gemm_bt<<<dim3(48, 16, 2), 256, 0, stream>>>(x_bf, wqkvT, part1, S_LEN, NQKV, 2048, D_DIM, D_DIM);
    epilogue1<<<dim3(32, 96), 256, 0, stream>>>(part1, qkv, vt);
  } else {
    gemm_bt<<<dim3(48, 16, 1), 256, 0, stream>>>(x_bf, wqkvT, qkv, S_LEN, NQKV, D_DIM, D_DIM, D_DIM);
    rope_kernel<<<dim3(S_LEN, 10), 256, 0, stream>>>(qkv);
    vt_kernel<<<dim3(32, 2, 8), 256, 0, stream>>>(qkv, vt);
  }

  attn_kernel<<<dim3(S_LEN / 128, NHEAD), 256, 0, stream>>>(qkv, vt, attn_o);

  gemm_bt<<<dim3(32, 16, 2), 256, 0, stream>>>(attn_o, woT, part2, S_LEN, D_DIM, 2048, D_DIM, D_DIM);
  reduce_out<<<4096, 256, 0, stream>>>(part2, out);
}

// Round 7
// 563.346 us; speedup vs baseline: 1.0849x; 1.0849x over previous
//
#include <hip/hip_runtime.h>
#include <cstdint>

#define S_LEN 2048
#define D_DIM 4096
#define NHEAD 32
#define NKVH  8
#define HDIM  128
#define NQKV  6144

typedef __bf16 bf16x8 __attribute__((ext_vector_type(8)));
typedef float floatx4 __attribute__((ext_vector_type(4)));
typedef unsigned short u16;
typedef unsigned int u32;

__device__ __forceinline__ u16 f2bf(float f) {
  u32 u = __builtin_bit_cast(u32, f);
  u += 0x7fffu + ((u >> 16) & 1u);
  return (u16)(u >> 16);
}
__device__ __forceinline__ float bf2f(u16 h) {
  u32 u = ((u32)h) << 16;
  return __builtin_bit_cast(float, u);
}

// async global->LDS, 16B per lane; LDS dest = wave-uniform base + lane*16
__device__ __forceinline__ void gll16(const void* g, const void* l) {
  __builtin_amdgcn_global_load_lds(
      (const __attribute__((address_space(1))) u32*)(unsigned long long)(uintptr_t)g,
      (__attribute__((address_space(3))) u32*)(u32)(uintptr_t)l, 16, 0, 0);
}

// ---------------- prep: x cast + all 4 weight transposes, one launch ----------------

__global__ __launch_bounds__(256) void prep_kernel(const float* __restrict__ x,
                                                   const float* __restrict__ Wq,
                                                   const float* __restrict__ Wk,
                                                   const float* __restrict__ Wv,
                                                   const float* __restrict__ Wo,
                                                   u16* __restrict__ x_bf,
                                                   u16* __restrict__ wqkvT,
                                                   u16* __restrict__ woT) {
  int id = blockIdx.x;
  if (id < 8192) {
    int i = (id * 256 + (int)threadIdx.x) * 4;
    float4 v = *(const float4*)(x + i);
    u32 lo = (u32)f2bf(v.x) | ((u32)f2bf(v.y) << 16);
    u32 hi = (u32)f2bf(v.z) | ((u32)f2bf(v.w) << 16);
    *(uint2*)(x_bf + i) = make_uint2(lo, hi);
    return;
  }
  id -= 8192;
  __shared__ float tile[64][65];
  const float* src;
  u16* dst;
  int N;
  if (id < 4096) {
    src = Wq; dst = wqkvT; N = 4096;
  } else if (id < 5120) {
    src = Wk; dst = wqkvT + (size_t)4096 * 4096; N = 1024; id -= 4096;
  } else if (id < 6144) {
    src = Wv; dst = wqkvT + (size_t)5120 * 4096; N = 1024; id -= 5120;
  } else {
    src = Wo; dst = woT; N = 4096; id -= 6144;
  }
  const int nb = id / 64, kb = id % 64;
  const int k0 = kb * 64, n0 = nb * 64;
  const int t = threadIdx.x;
  const int c4 = (t & 15) * 4, r0 = t >> 4;
#pragma unroll
  for (int p = 0; p < 4; ++p) {
    int r = r0 + p * 16;
    float4 v = *(const float4*)(src + (size_t)(k0 + r) * N + n0 + c4);
    tile[r][c4 + 0] = v.x;
    tile[r][c4 + 1] = v.y;
    tile[r][c4 + 2] = v.z;
    tile[r][c4 + 3] = v.w;
  }
  __syncthreads();
#pragma unroll
  for (int p = 0; p < 4; ++p) {
    int rr = r0 + p * 16;
    u32 a = (u32)f2bf(tile[c4 + 0][rr]) | ((u32)f2bf(tile[c4 + 1][rr]) << 16);
    u32 b = (u32)f2bf(tile[c4 + 2][rr]) | ((u32)f2bf(tile[c4 + 3][rr]) << 16);
    *(uint2*)(dst + (size_t)(n0 + rr) * 4096 + k0 + c4) = make_uint2(a, b);
  }
}

// ---------------- rope + v-transpose, one launch ----------------
// id < 20480: RoPE on q/k of qkv.  id >= 20480: V extract+transpose -> vt.
__global__ __launch_bounds__(256) void rope_vt_kernel(u16* __restrict__ qkv,
                                                      u16* __restrict__ vt) {
  int id = blockIdx.x;
  __shared__ u16 tile[64][65];
  if (id < 20480) {
    const int y = id >> 11, s = id & 2047;
    const int sub = threadIdx.x >> 6;
    const int i = threadIdx.x & 63;  // pair index
    const int hh = y * 4 + sub;
    const int colbase = (hh < NHEAD) ? hh * HDIM : D_DIM + (hh - NHEAD) * HDIM;
    u32* p = (u32*)(qkv + (size_t)s * NQKV + colbase) + i;
    u32 pr = *p;
    float x0 = bf2f((u16)(pr & 0xffffu));
    float x1 = bf2f((u16)(pr >> 16));
    float invf = expf(-(float)(2 * i) * (13.122363377404328f / 128.0f));
    float ang = (float)s * invf;
    float cs = cosf(ang), sn = sinf(ang);
    float o0 = x0 * cs - x1 * sn;
    float o1 = x0 * sn + x1 * cs;
    *p = (u32)f2bf(o0) | ((u32)f2bf(o1) << 16);
    return;
  }
  const int vb = id - 20480;  // 0..511
  const int hk = vb >> 6;
  const int d0 = ((vb >> 5) & 1) * 64;
  const int s0 = (vb & 31) * 64;
  const int t = threadIdx.x, c = t & 63, r0 = t >> 6;
#pragma unroll
  for (int p = 0; p < 16; ++p) {
    int r = r0 + p * 4;
    tile[r][c] = qkv[(size_t)(s0 + r) * NQKV + 5120 + hk * HDIM + d0 + c];
  }
  __syncthreads();
#pragma unroll
  for (int p = 0; p < 16; ++p) {
    int rr = r0 + p * 4;
    vt[((size_t)hk * HDIM + d0 + rr) * S_LEN + s0 + c] = tile[c][rr];
  }
}

// ---------------- GEMM: C[M,N] = A[M,K] * Bt[N,K]^T, BK=64 ----------------
// 32 MFMA per barrier-pair (2 k-chunks of 32), LDS 32 KB.

template <bool BF16_OUT>
__global__ __launch_bounds__(256) void gemm_bt(const u16* __restrict__ A,
                                               const u16* __restrict__ Bt,
                                               void* __restrict__ Cout,
                                               int M, int N, int K, int lda, int ldb) {
  __shared__ u16 As[2][128 * 32];
  __shared__ u16 Bs[2][128 * 32];
  const int tid = threadIdx.x;
  const int w = tid >> 6, lane = tid & 63;
  const int quad = lane >> 4, l15 = lane & 15;
  const int m0 = blockIdx.y * 128, n0 = blockIdx.x * 128;
  const int wm = (w & 1) * 64, wn = (w >> 1) * 64;
  floatx4 acc[4][4];
#pragma unroll
  for (int mi = 0; mi < 4; ++mi)
#pragma unroll
    for (int ni = 0; ni < 4; ++ni)
#pragma unroll
      for (int j = 0; j < 4; ++j) acc[mi][ni][j] = 0.0f;

  const int srow = w * 32 + (lane >> 2);
  const int kcol = (lane & 3) * 8;
  const u16* pA0 = A + (size_t)(m0 + srow) * lda + kcol;
  const u16* pA1 = pA0 + (size_t)16 * lda;
  const u16* pB0 = Bt + (size_t)(n0 + srow) * ldb + kcol;
  const u16* pB1 = pB0 + (size_t)16 * ldb;

  for (int k0 = 0; k0 < K; k0 += 64) {
#pragma unroll
    for (int c = 0; c < 2; ++c) {
      gll16(pA0 + k0 + c * 32, As[c] + (w * 32) * 32);
      gll16(pA1 + k0 + c * 32, As[c] + (w * 32 + 16) * 32);
      gll16(pB0 + k0 + c * 32, Bs[c] + (w * 32) * 32);
      gll16(pB1 + k0 + c * 32, Bs[c] + (w * 32 + 16) * 32);
    }
    __syncthreads();
#pragma unroll
    for (int c2 = 0; c2 < 2; ++c2) {
      bf16x8 a[4], b[4];
#pragma unroll
      for (int mi = 0; mi < 4; ++mi)
        a[mi] = *(const bf16x8*)(As[c2] + (wm + mi * 16 + l15) * 32 + quad * 8);
#pragma unroll
      for (int ni = 0; ni < 4; ++ni)
        b[ni] = *(const bf16x8*)(Bs[c2] + (wn + ni * 16 + l15) * 32 + quad * 8);
#pragma unroll
      for (int mi = 0; mi < 4; ++mi)
#pragma unroll
        for (int ni = 0; ni < 4; ++ni)
          acc[mi][ni] = __builtin_amdgcn_mfma_f32_16x16x32_bf16(a[mi], b[ni], acc[mi][ni], 0, 0, 0);
    }
    __syncthreads();
  }
#pragma unroll
  for (int mi = 0; mi < 4; ++mi)
#pragma unroll
    for (int ni = 0; ni < 4; ++ni) {
      int row = m0 + wm + mi * 16 + quad * 4;
      int col = n0 + wn + ni * 16 + l15;
#pragma unroll
      for (int j = 0; j < 4; ++j) {
        if (BF16_OUT)
          ((u16*)Cout)[(size_t)(row + j) * N + col] = f2bf(acc[mi][ni][j]);
        else
          ((float*)Cout)[(size_t)(row + j) * N + col] = acc[mi][ni][j];
      }
    }
}

// ---------------- flash attention (unchanged) ----------------

__global__ __launch_bounds__(256) void attn_kernel(const u16* __restrict__ qkv,
                                                   const u16* __restrict__ vt,
                                                   u16* __restrict__ attn_o) {
  __shared__ u16 Ks[4][64 * 32];
  __shared__ u16 Vs[2][128 * 32];
  __shared__ u16 Ps[4][16 * 64];
  const int tid = threadIdx.x, w = tid >> 6, lane = tid & 63;
  const int quad = lane >> 4, l15 = lane & 15;
  const int h = blockIdx.y, hk = h >> 2;
  const int bx = (h & 16) ? blockIdx.x : (gridDim.x - 1 - blockIdx.x);
  const int qb = bx * 128;
  const int mq0 = qb + w * 32;
  const float scale2 = 0.12751744591813488f;  // log2(e)/sqrt(128)
  const int sw = (l15 & 7) * 8;

  bf16x8 qfrag[2][4];
#pragma unroll
  for (int g = 0; g < 2; ++g) {
    const u16* qp = qkv + (size_t)(mq0 + g * 16 + l15) * NQKV + h * HDIM + quad * 8;
#pragma unroll
    for (int c = 0; c < 4; ++c) qfrag[g][c] = *(const bf16x8*)(qp + c * 32);
  }

  floatx4 o[2][8];
#pragma unroll
  for (int g = 0; g < 2; ++g)
#pragma unroll
    for (int nf = 0; nf < 8; ++nf)
#pragma unroll
      for (int j = 0; j < 4; ++j) o[g][nf][j] = 0.0f;
  float m_[2] = {-1e30f, -1e30f}, l_[2] = {0.0f, 0.0f};

  const int nkt = 2 * bx + 2;
  const int srow = lane >> 2;
  const int scol = (lane & 3) * 8;
  const u16* kst = qkv + (size_t)(w * 16 + srow) * NQKV + (D_DIM + hk * HDIM) + scol;
  const u16* vst0 = vt + ((size_t)hk * HDIM + w * 32 + srow) * S_LEN + scol;
  const u16* vst1 = vst0 + (size_t)16 * S_LEN;

  for (int kt = 0; kt < nkt; ++kt) {
    const int kb = kt * 64;
#pragma unroll
    for (int c = 0; c < 4; ++c)
      gll16(kst + (size_t)kb * NQKV + c * 32, &Ks[c][(w * 16) * 32]);
#pragma unroll
    for (int c = 0; c < 2; ++c) {
      gll16(vst0 + kb + c * 32, &Vs[c][(w * 32) * 32]);
      gll16(vst1 + kb + c * 32, &Vs[c][(w * 32 + 16) * 32]);
    }
    __syncthreads();

    if (kb <= mq0) {
      floatx4 sn[2][4];
#pragma unroll
      for (int g = 0; g < 2; ++g)
#pragma unroll
        for (int ki = 0; ki < 4; ++ki)
#pragma unroll
          for (int j = 0; j < 4; ++j) sn[g][ki][j] = 0.0f;
#pragma unroll
      for (int ki = 0; ki < 4; ++ki) {
        if (kb + ki * 16 <= mq0 + 31) {
          const bool g0on = (kb + ki * 16 <= mq0 + 15);
#pragma unroll
          for (int c = 0; c < 4; ++c) {
            bf16x8 kf = *(const bf16x8*)(&Ks[c][(ki * 16 + l15) * 32 + quad * 8]);
            sn[1][ki] = __builtin_amdgcn_mfma_f32_16x16x32_bf16(kf, qfrag[1][c], sn[1][ki], 0, 0, 0);
            if (g0on)
              sn[0][ki] = __builtin_amdgcn_mfma_f32_16x16x32_bf16(kf, qfrag[0][c], sn[0][ki], 0, 0, 0);
          }
        }
      }
      float alw[2];
      bf16x8 pa[2][2];
#pragma unroll
      for (int g = 0; g < 2; ++g) {
        const int qrow = mq0 + g * 16 + l15;
        const int qmax = mq0 + g * 16 + 15;
        float v[16];
        float mv = -1e30f;
#pragma unroll
        for (int ki = 0; ki < 4; ++ki) {
          if (kb + ki * 16 <= qmax) {
#pragma unroll
            for (int dj = 0; dj < 4; ++dj) {
              int key = kb + ki * 16 + quad * 4 + dj;
              float s = sn[g][ki][dj] * scale2;
              float vv = (key > qrow) ? -1e30f : s;
              v[ki * 4 + dj] = vv;
              mv = fmaxf(mv, vv);
            }
          } else {
#pragma unroll
            for (int dj = 0; dj < 4; ++dj) v[ki * 4 + dj] = -1e30f;
          }
        }
        mv = fmaxf(mv, __shfl_xor(mv, 16, 64));
        mv = fmaxf(mv, __shfl_xor(mv, 32, 64));
        float mn = fmaxf(m_[g], mv);
        float a_ = exp2f(m_[g] - mn);
        m_[g] = mn;
        float ps = 0.0f;
#pragma unroll
        for (int ki = 0; ki < 4; ++ki) {
          const int cs = (ki * 16 + quad * 4) ^ sw;
          if (kb + ki * 16 <= qmax) {
            float p0 = exp2f(v[ki * 4 + 0] - mn);
            float p1 = exp2f(v[ki * 4 + 1] - mn);
            float p2 = exp2f(v[ki * 4 + 2] - mn);
            float p3 = exp2f(v[ki * 4 + 3] - mn);
            ps += (p0 + p1) + (p2 + p3);
            u32 pk0 = (u32)f2bf(p0) | ((u32)f2bf(p1) << 16);
            u32 pk1 = (u32)f2bf(p2) | ((u32)f2bf(p3) << 16);
            *(uint2*)(&Ps[w][l15 * 64 + cs]) = make_uint2(pk0, pk1);
          } else {
            *(uint2*)(&Ps[w][l15 * 64 + cs]) = make_uint2(0u, 0u);
          }
        }
        ps += __shfl_xor(ps, 16, 64);
        ps += __shfl_xor(ps, 32, 64);
        l_[g] = l_[g] * a_ + ps;
        alw[g] = a_;
#pragma unroll
        for (int c2 = 0; c2 < 2; ++c2) {
          const int cs = (c2 * 32 + quad * 8) ^ sw;
          pa[g][c2] = *(const bf16x8*)(&Ps[w][l15 * 64 + cs]);
        }
      }
#pragma unroll
      for (int g = 0; g < 2; ++g) {
        float al[4];
#pragma unroll
        for (int dj = 0; dj < 4; ++dj) al[dj] = __shfl(alw[g], quad * 4 + dj, 16);
#pragma unroll
        for (int nf = 0; nf < 8; ++nf)
#pragma unroll
          for (int dj = 0; dj < 4; ++dj) o[g][nf][dj] *= al[dj];
      }
#pragma unroll
      for (int nf = 0; nf < 8; ++nf) {
        bf16x8 vb0 = *(const bf16x8*)(&Vs[0][(nf * 16 + l15) * 32 + quad * 8]);
        bf16x8 vb1 = *(const bf16x8*)(&Vs[1][(nf * 16 + l15) * 32 + quad * 8]);
#pragma unroll
        for (int g = 0; g < 2; ++g) {
          o[g][nf] = __builtin_amdgcn_mfma_f32_16x16x32_bf16(pa[g][0], vb0, o[g][nf], 0, 0, 0);
          o[g][nf] = __builtin_amdgcn_mfma_f32_16x16x32_bf16(pa[g][1], vb1, o[g][nf], 0, 0, 0);
        }
      }
    }
    __syncthreads();
  }

#pragma unroll
  for (int g = 0; g < 2; ++g) {
    float linv = 1.0f / l_[g];
    float rl[4];
#pragma unroll
    for (int dj = 0; dj < 4; ++dj) rl[dj] = __shfl(linv, quad * 4 + dj, 16);
#pragma unroll
    for (int nf = 0; nf < 8; ++nf)
#pragma unroll
      for (int dj = 0; dj < 4; ++dj) {
        int row = mq0 + g * 16 + quad * 4 + dj;
        int col = h * HDIM + nf * 16 + l15;
        attn_o[(size_t)row * D_DIM + col] = f2bf(o[g][nf][dj] * rl[dj]);
      }
  }
}

// ---------------- launcher ----------------

extern "C" void kernel_launch(void* const* d_in, const int* in_sizes, int n_in,
                              void* d_out, int out_size, void* d_ws, size_t ws_size,
                              hipStream_t stream) {
  const float* x  = (const float*)d_in[0];
  const float* Wq = (const float*)d_in[1];
  const float* Wk = (const float*)d_in[2];
  const float* Wv = (const float*)d_in[3];
  const float* Wo = (const float*)d_in[4];
  float* out = (float*)d_out;
  char* ws = (char*)d_ws;
  const size_t MB = 1024 * 1024;
  u16* x_bf   = (u16*)(ws);              // 16 MB   [2048][4096]
  u16* wqkvT  = (u16*)(ws + 16 * MB);    // 48 MB   [6144][4096]
  u16* woT    = (u16*)(ws + 64 * MB);    // 32 MB   [4096][4096]
  u16* qkv    = (u16*)(ws + 96 * MB);    // 24 MB   [2048][6144]
  u16* vt     = (u16*)(ws + 120 * MB);   //  4 MB   [8][128][2048]
  u16* attn_o = (u16*)(ws + 124 * MB);   // 16 MB   [2048][4096]

  prep_kernel<<<8192 + 10240, 256, 0, stream>>>(x, Wq, Wk, Wv, Wo, x_bf, wqkvT, woT);
  gemm_bt<true><<<dim3(48, 16), 256, 0, stream>>>(x_bf, wqkvT, qkv, S_LEN, NQKV, D_DIM, D_DIM, D_DIM);
  rope_vt_kernel<<<20480 + 512, 256, 0, stream>>>(qkv, vt);
  attn_kernel<<<dim3(S_LEN / 128, NHEAD), 256, 0, stream>>>(qkv, vt, attn_o);
  gemm_bt<false><<<dim3(32, 16), 256, 0, stream>>>(attn_o, woT, out, S_LEN, D_DIM, D_DIM, D_DIM, D_DIM);
}